// Round 14
// baseline (162.890 us; speedup 1.0000x reference)
//
#include <hip/hip_runtime.h>

#define N_NODES 50000
#define N_EDGES 800000
#define N_GRAPHS 64
#define D_IN 128
#define D_HID 64
#define D_OUT 32
#define POOL_TILE 512
#define G1_NT 8                            // nodes per wave in fused gather1+mm2
#define G2_NT 8                            // nodes per wave in gather2
#define PF1 8                              // prefetch slots/group in g1m2 (deg<=32)
#define PF2 4                              // prefetch slots/group in gather2 (deg<=32)
#define NPART ((N_NODES + 255) >> 8)       // 196 partitions of 256 nodes
#define BSTRIDE 5120                       // per-partition segment (mean 4096)
#define EPB 4096                           // edges per k_binA block

typedef __attribute__((ext_vector_type(8))) short bf16x8;
typedef __attribute__((ext_vector_type(4))) float f32x4;

__device__ __forceinline__ unsigned short bf16r(float f) {   // round-nearest-even
    unsigned int u = __float_as_uint(f);
    return (unsigned short)((u + 0x7fffu + ((u >> 16) & 1u)) >> 16);
}
// decode packed bf16 pair -> (lo, hi) floats, by value
__device__ __forceinline__ float2 bf2(unsigned int w) {
    return make_float2(__uint_as_float(w << 16), __uint_as_float(w & 0xffff0000u));
}

// -------------------------------------- init: W1 pack + zero psum/cursor ----
__global__ __launch_bounds__(256) void k_init(const float* __restrict__ W1,
                                              unsigned short* __restrict__ wph,
                                              unsigned short* __restrict__ wpl,
                                              float* __restrict__ psum,
                                              int* __restrict__ bin_cursor) {
    for (int i = threadIdx.x; i < N_GRAPHS * D_OUT; i += 256) psum[i] = 0.0f;
    for (int i = threadIdx.x; i < NPART; i += 256) bin_cursor[i] = 0;
    for (int idx = threadIdx.x; idx < D_IN * D_HID; idx += 256) {
        int k = idx >> 6, c = idx & 63;          // coalesced W1 read
        float w = W1[idx];
        unsigned int b = __float_as_uint(w);
        unsigned short h = (unsigned short)(b >> 16);
        float fh = __uint_as_float(b & 0xffff0000u);
        unsigned short l = (unsigned short)(__float_as_uint(w - fh) >> 16);
        int kt = k >> 5, oct = (k >> 3) & 3, i = k & 7;
        int nt = c >> 4, col = c & 15;
        int dst = ((kt * 4 + nt) * 64 + (oct * 16 + col)) * 8 + i;
        wph[dst] = h;
        wpl[dst] = l;
    }
}

// ------------------------------------------------------------- bin pass -----
// Entry pack: src (16b) | dst_local (8b) | partition (8b).
__global__ __launch_bounds__(256) void k_binA(const int* __restrict__ src,
                                              const int* __restrict__ dst,
                                              int* __restrict__ bin_cursor,
                                              unsigned int* __restrict__ binbuf) {
    __shared__ int cnt[NPART];
    __shared__ int boff[NPART];
    __shared__ int gbase[NPART];
    __shared__ int tmp[256];
    __shared__ unsigned int stage[EPB];

    const int tid = threadIdx.x;
    const int e0 = blockIdx.x * EPB;
    const int nvalid = min(EPB, N_EDGES - e0);

    for (int i = tid; i < NPART; i += 256) cnt[i] = 0;
    __syncthreads();

    unsigned int ee[16];
    const int i40 = e0 >> 2;
    #pragma unroll
    for (int j = 0; j < 4; ++j) {
        int i4 = i40 + j * 256 + tid;
        if (4 * i4 + 3 < N_EDGES) {
            int4 s4 = ((const int4*)src)[i4];
            int4 d4 = ((const int4*)dst)[i4];
            ee[4*j+0] = (unsigned)(s4.x | ((d4.x & 255) << 16) | ((d4.x >> 8) << 24));
            ee[4*j+1] = (unsigned)(s4.y | ((d4.y & 255) << 16) | ((d4.y >> 8) << 24));
            ee[4*j+2] = (unsigned)(s4.z | ((d4.z & 255) << 16) | ((d4.z >> 8) << 24));
            ee[4*j+3] = (unsigned)(s4.w | ((d4.w & 255) << 16) | ((d4.w >> 8) << 24));
        } else {
            #pragma unroll
            for (int k = 0; k < 4; ++k) {
                int e = 4 * i4 + k;
                if (e < N_EDGES) {
                    int s = src[e], d = dst[e];
                    ee[4*j+k] = (unsigned)(s | ((d & 255) << 16) | ((d >> 8) << 24));
                } else {
                    ee[4*j+k] = 0xFFFFFFFFu;   // p=255 >= NPART -> skipped
                }
            }
        }
    }

    #pragma unroll
    for (int j = 0; j < 16; ++j) {
        unsigned int p = ee[j] >> 24;
        if (p < NPART) atomicAdd(&cnt[p], 1);
    }
    __syncthreads();

    tmp[tid] = (tid < NPART) ? cnt[tid] : 0;
    __syncthreads();
    for (int off = 1; off < 256; off <<= 1) {
        int t = (tid >= off) ? tmp[tid - off] : 0;
        __syncthreads();
        tmp[tid] += t;
        __syncthreads();
    }
    if (tid < NPART) {
        int c = cnt[tid];
        int b = tmp[tid] - c;
        boff[tid] = b;
        gbase[tid] = atomicAdd(&bin_cursor[tid], c);
        cnt[tid] = b;               // becomes local cursor
    }
    __syncthreads();

    #pragma unroll
    for (int j = 0; j < 16; ++j) {
        unsigned int p = ee[j] >> 24;
        if (p < NPART) {
            int lp = atomicAdd(&cnt[p], 1);
            stage[lp] = ee[j];
        }
    }
    __syncthreads();

    for (int j = tid; j < nvalid; j += 256) {
        unsigned int e = stage[j];
        int p = e >> 24;
        binbuf[(size_t)p * BSTRIDE + gbase[p] + (j - boff[p])] = e;
    }
}

// ------------------------------------------- fused CSR build per partition --
__global__ __launch_bounds__(256) void k_csr(const int* __restrict__ bin_cursor,
                                             const unsigned int* __restrict__ binbuf,
                                             int* __restrict__ rowptr,
                                             float* __restrict__ dinv,
                                             int* __restrict__ csr_src) {
    __shared__ int sh[256];
    const int p = blockIdx.x, tid = threadIdx.x;

    sh[tid] = (tid < p) ? bin_cursor[tid] : 0;
    __syncthreads();
    for (int off = 128; off; off >>= 1) {
        if (tid < off) sh[tid] += sh[tid + off];
        __syncthreads();
    }
    const int offset = sh[0];
    __syncthreads();

    sh[tid] = 0;
    __syncthreads();
    const unsigned int* b = binbuf + (size_t)p * BSTRIDE;
    const int n = bin_cursor[p];
    for (int j = tid; j < n; j += 256) atomicAdd(&sh[(b[j] >> 16) & 255], 1);
    __syncthreads();
    const int deg = sh[tid];
    __syncthreads();

    sh[tid] = deg;
    __syncthreads();
    for (int off = 1; off < 256; off <<= 1) {
        int t = (tid >= off) ? sh[tid - off] : 0;
        __syncthreads();
        sh[tid] += t;
        __syncthreads();
    }
    const int rp = offset + sh[tid] - deg;
    const int node = p * 256 + tid;
    if (node < N_NODES) {
        rowptr[node] = rp;
        dinv[node] = rsqrtf((float)(deg + 1));   // +1 self-loop
    }
    if (node == N_NODES) rowptr[N_NODES] = N_EDGES;
    __syncthreads();

    sh[tid] = rp;
    __syncthreads();
    for (int j = tid; j < n; j += 256) {
        unsigned int e = b[j];
        int pos = atomicAdd(&sh[(e >> 16) & 255], 1);
        csr_src[pos] = (int)(e & 0xFFFFu);
    }
}

// ------------------------------------------------- conv1 matmul (MFMA) ------
// hs1[v] = bf16(((x[v]/max(rowsum,1)) @ W1) * dinv[v]), split-bf16 (3 MFMA).
__global__ __launch_bounds__(256) void k_mm1(const float* __restrict__ x,
                                             const unsigned short* __restrict__ wph,
                                             const unsigned short* __restrict__ wpl,
                                             const float* __restrict__ dinv,
                                             unsigned short* __restrict__ hs1b) {
    const int lane = threadIdx.x & 63;
    const int gw = blockIdx.x * 4 + (threadIdx.x >> 6);
    const int node0 = gw * 16;
    if (node0 >= N_NODES) return;
    const int r16 = lane & 15, oct = lane >> 4;
    const int rowAc = min(node0 + r16, N_NODES - 1);   // clamp tail (stores guarded)

    const float* xr = x + (size_t)rowAc * D_IN + oct * 32;
    float rs = 0.f;
    #pragma unroll
    for (int q = 0; q < 8; ++q) {
        float4 v = ((const float4*)xr)[q];
        rs += (v.x + v.y) + (v.z + v.w);
    }
    rs += __shfl_xor(rs, 16, 64);
    rs += __shfl_xor(rs, 32, 64);
    const float ls = (1.0f / fmaxf(rs, 1.0f)) * dinv[rowAc];

    f32x4 acc[4] = {};   // one per 16-col ntile
    #pragma unroll
    for (int kt = 0; kt < 4; ++kt) {
        const float* ap = x + (size_t)rowAc * D_IN + kt * 32 + oct * 8;
        float4 a0 = ((const float4*)ap)[0];
        float4 a1 = ((const float4*)ap)[1];
        float f[8] = {a0.x, a0.y, a0.z, a0.w, a1.x, a1.y, a1.z, a1.w};
        bf16x8 ahi, alo;
        #pragma unroll
        for (int j = 0; j < 8; ++j) {
            float fs = f[j] * ls;
            unsigned int b = __float_as_uint(fs);
            ahi[j] = (short)(b >> 16);
            float fh = __uint_as_float(b & 0xffff0000u);
            alo[j] = (short)(__float_as_uint(fs - fh) >> 16);
        }
        #pragma unroll
        for (int nt = 0; nt < 4; ++nt) {
            int fo = ((kt * 4 + nt) * 64 + lane) * 8;
            bf16x8 bh = *(const bf16x8*)(wph + fo);
            bf16x8 bl = *(const bf16x8*)(wpl + fo);
            acc[nt] = __builtin_amdgcn_mfma_f32_16x16x32_bf16(ahi, bh, acc[nt], 0, 0, 0);
            acc[nt] = __builtin_amdgcn_mfma_f32_16x16x32_bf16(ahi, bl, acc[nt], 0, 0, 0);
            acc[nt] = __builtin_amdgcn_mfma_f32_16x16x32_bf16(alo, bh, acc[nt], 0, 0, 0);
        }
    }
    // C/D: col = lane&15, row = oct*4 + r   [m89 layout]
    #pragma unroll
    for (int nt = 0; nt < 4; ++nt) {
        #pragma unroll
        for (int r = 0; r < 4; ++r) {
            int node = node0 + oct * 4 + r;
            if (node < N_NODES)
                hs1b[(size_t)node * D_HID + nt * 16 + r16] = bf16r(acc[nt][r]);
        }
    }
}

// ----------------------------------------- fused gather1 + conv2 matmul -----
// DEPTH-2 row pipeline: rows for node t were issued at iteration t-2 (two
// full iterations of latency cover). Per iteration t: (1) raw idx(t+2)
// unpredicated, (2) accumulate(t), (3) issue rows(t+2) with late clamp
// (end(t+2) resident after accumulate), (4) butterfly+mm2, (5) ring shift.
__global__ __launch_bounds__(256) void k_g1m2(const int* __restrict__ rowptr,
                                              const int* __restrict__ csr_src,
                                              const unsigned short* __restrict__ hs1b,
                                              const float* __restrict__ dinv,
                                              const float* __restrict__ b1,
                                              const float* __restrict__ W2,
                                              unsigned short* __restrict__ hs2b) {
    const int lane = threadIdx.x & 63;
    const int g = lane >> 4;          // gather group 0..3
    const int q = lane & 15;          // channel-quad (h1 channels 4q..4q+3)
    const int c = lane & 31;          // output channel
    const int kh = lane >> 5;         // k-half for mm2

    float w2r[32];
    #pragma unroll
    for (int j = 0; j < 32; ++j) w2r[j] = W2[(kh * 32 + j) * D_OUT + c];  // coalesced
    const f32x4 bb = ((const f32x4*)b1)[q];

    const int node0 = (blockIdx.x * 4 + (threadIdx.x >> 6)) * G1_NT;
    if (node0 >= N_NODES) return;

    // ---- prologue: rows(0) and rows(1) ----
    int begA = rowptr[node0];
    int endA = rowptr[node0 + 1];
    uint2 rowsA[PF1];
    {
        int raw[PF1];
        #pragma unroll
        for (int i = 0; i < PF1; ++i) raw[i] = csr_src[begA + g + 4 * i] & 0xFFFF;
        #pragma unroll
        for (int i = 0; i < PF1; ++i) {
            int idx = (begA + g + 4 * i < endA) ? raw[i] : 0;
            rowsA[i] = ((const uint2*)(hs1b + (size_t)idx * D_HID))[q];
        }
    }
    int begB = endA, endB = endA;
    uint2 rowsB[PF1];
    if (node0 + 1 < N_NODES) {
        endB = rowptr[node0 + 2];
        int raw[PF1];
        #pragma unroll
        for (int i = 0; i < PF1; ++i) raw[i] = csr_src[begB + g + 4 * i] & 0xFFFF;
        #pragma unroll
        for (int i = 0; i < PF1; ++i) {
            int idx = (begB + g + 4 * i < endB) ? raw[i] : 0;
            rowsB[i] = ((const uint2*)(hs1b + (size_t)idx * D_HID))[q];
        }
    }

    for (int t = 0; t < G1_NT; ++t) {
        const int v = node0 + t;
        if (v >= N_NODES) break;
        const bool haveN1 = (t < G1_NT - 1) && (v + 1 < N_NODES);
        const bool haveN2 = (t < G1_NT - 2) && (v + 2 < N_NODES);

        // (1) raw index loads for node t+2 (unpredicated; beg = endB resident)
        const int begCC = endB;
        int endCC = endB;
        int rawCC[PF1];
        if (haveN2) {
            endCC = rowptr[v + 3];
            #pragma unroll
            for (int i = 0; i < PF1; ++i) rawCC[i] = csr_src[begCC + g + 4 * i] & 0xFFFF;
        }

        // (2) accumulate current node — rowsA issued two iterations ago
        f32x4 acc0 = {0,0,0,0}, acc1 = {0,0,0,0};
        if (g == 0) {   // self-loop
            uint2 w = ((const uint2*)(hs1b + (size_t)v * D_HID))[q];
            float2 t0 = bf2(w.x), t1 = bf2(w.y);
            acc0[0] += t0.x; acc0[1] += t0.y; acc0[2] += t1.x; acc0[3] += t1.y;
        }
        #pragma unroll
        for (int i = 0; i < PF1; ++i) {
            if (begA + g + 4 * i < endA) {
                float2 t0 = bf2(rowsA[i].x), t1 = bf2(rowsA[i].y);
                if (i & 1) { acc1[0]+=t0.x; acc1[1]+=t0.y; acc1[2]+=t1.x; acc1[3]+=t1.y; }
                else       { acc0[0]+=t0.x; acc0[1]+=t0.y; acc0[2]+=t1.x; acc0[3]+=t1.y; }
            }
        }
        for (int e = begA + g + 4 * PF1; e < endA; e += 4) {   // rare deg>32 tail
            int s = csr_src[e];
            uint2 w = ((const uint2*)(hs1b + (size_t)s * D_HID))[q];
            float2 t0 = bf2(w.x), t1 = bf2(w.y);
            acc0[0]+=t0.x; acc0[1]+=t0.y; acc0[2]+=t1.x; acc0[3]+=t1.y;
        }
        f32x4 acc = acc0 + acc1;

        // (3) issue rows for node t+2 with LATE clamp (endCC resident by now)
        uint2 rowsCC[PF1];
        if (haveN2) {
            #pragma unroll
            for (int i = 0; i < PF1; ++i) {
                int idx = (begCC + g + 4 * i < endCC) ? rawCC[i] : 0;
                rowsCC[i] = ((const uint2*)(hs1b + (size_t)idx * D_HID))[q];
            }
        }

        // (4) butterfly across groups
        #pragma unroll
        for (int m = 16; m <= 32; m <<= 1) {
            f32x4 o;
            o[0] = __shfl_xor(acc[0], m, 64);
            o[1] = __shfl_xor(acc[1], m, 64);
            o[2] = __shfl_xor(acc[2], m, 64);
            o[3] = __shfl_xor(acc[3], m, 64);
            acc += o;
        }

        const float dv = dinv[v];
        f32x4 h;
        #pragma unroll
        for (int j = 0; j < 4; ++j) h[j] = fmaxf(dv * acc[j] + bb[j], 0.0f);

        // mm2: k = kh*32 + 4*qq + j  ->  quad Q = kh*8+qq held by lane Q
        float a = 0.0f;
        #pragma unroll
        for (int qq = 0; qq < 8; ++qq) {
            const int Q = kh * 8 + qq;
            a += __shfl(h[0], Q, 64) * w2r[4 * qq + 0];
            a += __shfl(h[1], Q, 64) * w2r[4 * qq + 1];
            a += __shfl(h[2], Q, 64) * w2r[4 * qq + 2];
            a += __shfl(h[3], Q, 64) * w2r[4 * qq + 3];
        }
        a += __shfl_xor(a, 32, 64);    // sum the two k-halves
        if (kh == 0) hs2b[(size_t)v * D_OUT + c] = bf16r(a * dv);

        // (5) ring shift
        if (haveN1) {
            begA = begB; endA = endB;
            begB = begCC; endB = endCC;
            #pragma unroll
            for (int i = 0; i < PF1; ++i) { rowsA[i] = rowsB[i]; rowsB[i] = rowsCC[i]; }
        }
    }
}

// -------------------------------------------------------------- gather2 -----
// Depth-2 pipeline, same discipline. 8 groups x 8 lanes; PF2=4 covers deg<=32.
// Fused epilogue: p = relu(dinv*agg + b2).
__global__ __launch_bounds__(256) void k_gather2(const int* __restrict__ rowptr,
                                                 const int* __restrict__ csr_src,
                                                 const unsigned short* __restrict__ hs2b,
                                                 const float* __restrict__ dinv,
                                                 const float* __restrict__ b2,
                                                 float* __restrict__ p) {
    const int lane = threadIdx.x & 63;
    const int g = lane >> 3;          // group 0..7
    const int q = lane & 7;           // channel-quad index

    const int node0 = (blockIdx.x * 4 + (threadIdx.x >> 6)) * G2_NT;
    if (node0 >= N_NODES) return;
    const f32x4 bb = ((const f32x4*)b2)[q];

    int begA = rowptr[node0];
    int endA = rowptr[node0 + 1];
    uint2 rowsA[PF2];
    {
        int raw[PF2];
        #pragma unroll
        for (int i = 0; i < PF2; ++i) raw[i] = csr_src[begA + g + 8 * i] & 0xFFFF;
        #pragma unroll
        for (int i = 0; i < PF2; ++i) {
            int idx = (begA + g + 8 * i < endA) ? raw[i] : 0;
            rowsA[i] = ((const uint2*)(hs2b + (size_t)idx * D_OUT))[q];
        }
    }
    int begB = endA, endB = endA;
    uint2 rowsB[PF2];
    if (node0 + 1 < N_NODES) {
        endB = rowptr[node0 + 2];
        int raw[PF2];
        #pragma unroll
        for (int i = 0; i < PF2; ++i) raw[i] = csr_src[begB + g + 8 * i] & 0xFFFF;
        #pragma unroll
        for (int i = 0; i < PF2; ++i) {
            int idx = (begB + g + 8 * i < endB) ? raw[i] : 0;
            rowsB[i] = ((const uint2*)(hs2b + (size_t)idx * D_OUT))[q];
        }
    }

    for (int t = 0; t < G2_NT; ++t) {
        const int v = node0 + t;
        if (v >= N_NODES) break;
        const bool haveN1 = (t < G2_NT - 1) && (v + 1 < N_NODES);
        const bool haveN2 = (t < G2_NT - 2) && (v + 2 < N_NODES);

        const int begCC = endB;
        int endCC = endB;
        int rawCC[PF2];
        if (haveN2) {
            endCC = rowptr[v + 3];
            #pragma unroll
            for (int i = 0; i < PF2; ++i) rawCC[i] = csr_src[begCC + g + 8 * i] & 0xFFFF;
        }

        f32x4 acc = {0,0,0,0};
        if (g == 0) {   // self-loop
            uint2 w = ((const uint2*)(hs2b + (size_t)v * D_OUT))[q];
            float2 t0 = bf2(w.x), t1 = bf2(w.y);
            acc[0] += t0.x; acc[1] += t0.y; acc[2] += t1.x; acc[3] += t1.y;
        }
        #pragma unroll
        for (int i = 0; i < PF2; ++i) {
            if (begA + g + 8 * i < endA) {
                float2 t0 = bf2(rowsA[i].x), t1 = bf2(rowsA[i].y);
                acc[0] += t0.x; acc[1] += t0.y; acc[2] += t1.x; acc[3] += t1.y;
            }
        }
        for (int e = begA + g + 8 * PF2; e < endA; e += 8) {   // rare deg>32 tail
            int s = csr_src[e];
            uint2 w = ((const uint2*)(hs2b + (size_t)s * D_OUT))[q];
            float2 t0 = bf2(w.x), t1 = bf2(w.y);
            acc[0] += t0.x; acc[1] += t0.y; acc[2] += t1.x; acc[3] += t1.y;
        }

        uint2 rowsCC[PF2];
        if (haveN2) {
            #pragma unroll
            for (int i = 0; i < PF2; ++i) {
                int idx = (begCC + g + 8 * i < endCC) ? rawCC[i] : 0;
                rowsCC[i] = ((const uint2*)(hs2b + (size_t)idx * D_OUT))[q];
            }
        }

        #pragma unroll
        for (int m = 8; m <= 32; m <<= 1) {
            f32x4 o;
            o[0] = __shfl_xor(acc[0], m, 64);
            o[1] = __shfl_xor(acc[1], m, 64);
            o[2] = __shfl_xor(acc[2], m, 64);
            o[3] = __shfl_xor(acc[3], m, 64);
            acc += o;
        }

        if (g == 0) {
            const float dv = dinv[v];
            f32x4 r;
            #pragma unroll
            for (int j = 0; j < 4; ++j) r[j] = fmaxf(dv * acc[j] + bb[j], 0.0f);
            ((f32x4*)(p + (size_t)v * D_OUT))[q] = r;
        }

        if (haveN1) {
            begA = begB; endA = endB;
            begB = begCC; endB = endCC;
            #pragma unroll
            for (int i = 0; i < PF2; ++i) { rowsA[i] = rowsB[i]; rowsB[i] = rowsCC[i]; }
        }
    }
}

// ----------------------------------------------------------- mean pool ------
__global__ __launch_bounds__(256) void k_pool(const float* __restrict__ p,
                                              const int* __restrict__ batch,
                                              float* __restrict__ psum) {
    const int c = threadIdx.x & 31;
    const int slot = threadIdx.x >> 5;
    const int base = blockIdx.x * POOL_TILE;

    float acc = 0.0f;
    int curg = -1;
    for (int j = slot; j < POOL_TILE; j += 8) {
        int node = base + j;
        if (node >= N_NODES) break;
        float hv = p[(size_t)node * D_OUT + c];
        int g = batch[node];
        if (g != curg) {
            if (curg >= 0) atomicAdd(&psum[curg * D_OUT + c], acc);
            curg = g;
            acc = 0.0f;
        }
        acc += hv;
    }
    if (curg >= 0) atomicAdd(&psum[curg * D_OUT + c], acc);
}

__global__ __launch_bounds__(256) void k_final(const float* __restrict__ psum,
                                               const int* __restrict__ batch,
                                               float* __restrict__ out) {
    int i = blockIdx.x * 256 + threadIdx.x;
    if (i < N_GRAPHS * D_OUT) {
        int g = i >> 5;   // D_OUT == 32
        int lo = 0, hi = N_NODES;
        while (lo < hi) { int m = (lo + hi) >> 1; if (batch[m] < g) lo = m + 1; else hi = m; }
        int lb = lo;
        lo = 0; hi = N_NODES;
        while (lo < hi) { int m = (lo + hi) >> 1; if (batch[m] <= g) lo = m + 1; else hi = m; }
        float cnt = (float)(lo - lb);
        out[i] = psum[i] / fmaxf(cnt, 1.0f);
    }
}

// ---------------------------------------------------------------------------
extern "C" void kernel_launch(void* const* d_in, const int* in_sizes, int n_in,
                              void* d_out, int out_size, void* d_ws, size_t ws_size,
                              hipStream_t stream) {
    const float* x     = (const float*)d_in[0];
    const int*   edge  = (const int*)d_in[1];   // [2, E]
    const int*   batch = (const int*)d_in[2];   // [N] sorted
    const float* W1    = (const float*)d_in[3];
    const float* b1    = (const float*)d_in[4];
    const float* W2    = (const float*)d_in[5];
    const float* b2    = (const float*)d_in[6];
    float* out = (float*)d_out;

    const int* src = edge;
    const int* dst = edge + N_EDGES;

    float* ws   = (float*)d_ws;
    float* dinv = ws;                                        // N floats
    unsigned short* hs1b = (unsigned short*)(dinv + N_NODES);     // N*64 bf16
    unsigned short* hs2b = hs1b + (size_t)N_NODES * D_HID;        // N*32 bf16
    float* p    = (float*)(hs2b + (size_t)N_NODES * D_OUT);       // N*32 f32
    float* psum = p + (size_t)N_NODES * D_OUT;                    // G*32
    int* bin_cursor = (int*)(psum + N_GRAPHS * D_OUT);            // NPART
    int* rowptr  = bin_cursor + NPART;                            // N+1
    int* csr_src = rowptr + N_NODES + 1;                          // E
    unsigned int* binbuf = (unsigned int*)(csr_src + N_EDGES);    // NPART*BSTRIDE
    unsigned short* wph = (unsigned short*)(binbuf + (size_t)NPART * BSTRIDE);  // 8192
    unsigned short* wpl = wph + D_IN * D_HID;                                   // 8192

    k_init   <<<1, 256, 0, stream>>>(W1, wph, wpl, psum, bin_cursor);
    k_binA   <<<(N_EDGES + EPB - 1) / EPB, 256, 0, stream>>>(src, dst, bin_cursor, binbuf);
    k_csr    <<<NPART, 256, 0, stream>>>(bin_cursor, binbuf, rowptr, dinv, csr_src);
    k_mm1    <<<(N_NODES + 63) / 64, 256, 0, stream>>>(x, wph, wpl, dinv, hs1b);
    k_g1m2   <<<(N_NODES + 4 * G1_NT - 1) / (4 * G1_NT), 256, 0, stream>>>(rowptr, csr_src, hs1b, dinv, b1, W2, hs2b);
    k_gather2<<<(N_NODES + 4 * G2_NT - 1) / (4 * G2_NT), 256, 0, stream>>>(rowptr, csr_src, hs2b, dinv, b2, p);
    k_pool   <<<(N_NODES + POOL_TILE - 1) / POOL_TILE, 256, 0, stream>>>(p, batch, psum);
    k_final  <<<(N_GRAPHS * D_OUT + 255) / 256, 256, 0, stream>>>(psum, batch, out);
}

// Round 15
// 126.619 us; speedup vs baseline: 1.2865x; 1.2865x over previous
//
#include <hip/hip_runtime.h>

#define N_NODES 50000
#define N_EDGES 800000
#define N_GRAPHS 64
#define D_IN 128
#define D_HID 64
#define D_OUT 32
#define POOL_TILE 512
#define G1_NT 4                            // nodes per wave in fused gather1+mm2 (TLP: 2x waves vs R13)
#define G2_NT 4                            // nodes per wave in gather2
#define PF1 8                              // prefetch slots/group in g1m2 (deg<=32)
#define PF2 4                              // prefetch slots/group in gather2 (deg<=32)
#define NPART ((N_NODES + 255) >> 8)       // 196 partitions of 256 nodes
#define BSTRIDE 5120                       // per-partition segment (mean 4096)
#define EPB 4096                           // edges per k_binA block

typedef __attribute__((ext_vector_type(8))) short bf16x8;
typedef __attribute__((ext_vector_type(4))) float f32x4;

__device__ __forceinline__ unsigned short bf16r(float f) {   // round-nearest-even
    unsigned int u = __float_as_uint(f);
    return (unsigned short)((u + 0x7fffu + ((u >> 16) & 1u)) >> 16);
}
// decode packed bf16 pair -> (lo, hi) floats, by value
__device__ __forceinline__ float2 bf2(unsigned int w) {
    return make_float2(__uint_as_float(w << 16), __uint_as_float(w & 0xffff0000u));
}

// -------------------------------------- init: W1 pack + zero psum/cursor ----
__global__ __launch_bounds__(256) void k_init(const float* __restrict__ W1,
                                              unsigned short* __restrict__ wph,
                                              unsigned short* __restrict__ wpl,
                                              float* __restrict__ psum,
                                              int* __restrict__ bin_cursor) {
    for (int i = threadIdx.x; i < N_GRAPHS * D_OUT; i += 256) psum[i] = 0.0f;
    for (int i = threadIdx.x; i < NPART; i += 256) bin_cursor[i] = 0;
    for (int idx = threadIdx.x; idx < D_IN * D_HID; idx += 256) {
        int k = idx >> 6, c = idx & 63;          // coalesced W1 read
        float w = W1[idx];
        unsigned int b = __float_as_uint(w);
        unsigned short h = (unsigned short)(b >> 16);
        float fh = __uint_as_float(b & 0xffff0000u);
        unsigned short l = (unsigned short)(__float_as_uint(w - fh) >> 16);
        int kt = k >> 5, oct = (k >> 3) & 3, i = k & 7;
        int nt = c >> 4, col = c & 15;
        int dst = ((kt * 4 + nt) * 64 + (oct * 16 + col)) * 8 + i;
        wph[dst] = h;
        wpl[dst] = l;
    }
}

// ------------------------------------------------------------- bin pass -----
// Entry pack: src (16b) | dst_local (8b) | partition (8b).
__global__ __launch_bounds__(256) void k_binA(const int* __restrict__ src,
                                              const int* __restrict__ dst,
                                              int* __restrict__ bin_cursor,
                                              unsigned int* __restrict__ binbuf) {
    __shared__ int cnt[NPART];
    __shared__ int boff[NPART];
    __shared__ int gbase[NPART];
    __shared__ int tmp[256];
    __shared__ unsigned int stage[EPB];

    const int tid = threadIdx.x;
    const int e0 = blockIdx.x * EPB;
    const int nvalid = min(EPB, N_EDGES - e0);

    for (int i = tid; i < NPART; i += 256) cnt[i] = 0;
    __syncthreads();

    unsigned int ee[16];
    const int i40 = e0 >> 2;
    #pragma unroll
    for (int j = 0; j < 4; ++j) {
        int i4 = i40 + j * 256 + tid;
        if (4 * i4 + 3 < N_EDGES) {
            int4 s4 = ((const int4*)src)[i4];
            int4 d4 = ((const int4*)dst)[i4];
            ee[4*j+0] = (unsigned)(s4.x | ((d4.x & 255) << 16) | ((d4.x >> 8) << 24));
            ee[4*j+1] = (unsigned)(s4.y | ((d4.y & 255) << 16) | ((d4.y >> 8) << 24));
            ee[4*j+2] = (unsigned)(s4.z | ((d4.z & 255) << 16) | ((d4.z >> 8) << 24));
            ee[4*j+3] = (unsigned)(s4.w | ((d4.w & 255) << 16) | ((d4.w >> 8) << 24));
        } else {
            #pragma unroll
            for (int k = 0; k < 4; ++k) {
                int e = 4 * i4 + k;
                if (e < N_EDGES) {
                    int s = src[e], d = dst[e];
                    ee[4*j+k] = (unsigned)(s | ((d & 255) << 16) | ((d >> 8) << 24));
                } else {
                    ee[4*j+k] = 0xFFFFFFFFu;   // p=255 >= NPART -> skipped
                }
            }
        }
    }

    #pragma unroll
    for (int j = 0; j < 16; ++j) {
        unsigned int p = ee[j] >> 24;
        if (p < NPART) atomicAdd(&cnt[p], 1);
    }
    __syncthreads();

    tmp[tid] = (tid < NPART) ? cnt[tid] : 0;
    __syncthreads();
    for (int off = 1; off < 256; off <<= 1) {
        int t = (tid >= off) ? tmp[tid - off] : 0;
        __syncthreads();
        tmp[tid] += t;
        __syncthreads();
    }
    if (tid < NPART) {
        int c = cnt[tid];
        int b = tmp[tid] - c;
        boff[tid] = b;
        gbase[tid] = atomicAdd(&bin_cursor[tid], c);
        cnt[tid] = b;               // becomes local cursor
    }
    __syncthreads();

    #pragma unroll
    for (int j = 0; j < 16; ++j) {
        unsigned int p = ee[j] >> 24;
        if (p < NPART) {
            int lp = atomicAdd(&cnt[p], 1);
            stage[lp] = ee[j];
        }
    }
    __syncthreads();

    for (int j = tid; j < nvalid; j += 256) {
        unsigned int e = stage[j];
        int p = e >> 24;
        binbuf[(size_t)p * BSTRIDE + gbase[p] + (j - boff[p])] = e;
    }
}

// ------------------------------------------- fused CSR build per partition --
__global__ __launch_bounds__(256) void k_csr(const int* __restrict__ bin_cursor,
                                             const unsigned int* __restrict__ binbuf,
                                             int* __restrict__ rowptr,
                                             float* __restrict__ dinv,
                                             int* __restrict__ csr_src) {
    __shared__ int sh[256];
    const int p = blockIdx.x, tid = threadIdx.x;

    sh[tid] = (tid < p) ? bin_cursor[tid] : 0;
    __syncthreads();
    for (int off = 128; off; off >>= 1) {
        if (tid < off) sh[tid] += sh[tid + off];
        __syncthreads();
    }
    const int offset = sh[0];
    __syncthreads();

    sh[tid] = 0;
    __syncthreads();
    const unsigned int* b = binbuf + (size_t)p * BSTRIDE;
    const int n = bin_cursor[p];
    for (int j = tid; j < n; j += 256) atomicAdd(&sh[(b[j] >> 16) & 255], 1);
    __syncthreads();
    const int deg = sh[tid];
    __syncthreads();

    sh[tid] = deg;
    __syncthreads();
    for (int off = 1; off < 256; off <<= 1) {
        int t = (tid >= off) ? sh[tid - off] : 0;
        __syncthreads();
        sh[tid] += t;
        __syncthreads();
    }
    const int rp = offset + sh[tid] - deg;
    const int node = p * 256 + tid;
    if (node < N_NODES) {
        rowptr[node] = rp;
        dinv[node] = rsqrtf((float)(deg + 1));   // +1 self-loop
    }
    if (node == N_NODES) rowptr[N_NODES] = N_EDGES;
    __syncthreads();

    sh[tid] = rp;
    __syncthreads();
    for (int j = tid; j < n; j += 256) {
        unsigned int e = b[j];
        int pos = atomicAdd(&sh[(e >> 16) & 255], 1);
        csr_src[pos] = (int)(e & 0xFFFFu);
    }
}

// ------------------------------------------------- conv1 matmul (MFMA) ------
// hs1[v] = bf16(((x[v]/max(rowsum,1)) @ W1) * dinv[v]), split-bf16 (3 MFMA).
__global__ __launch_bounds__(256) void k_mm1(const float* __restrict__ x,
                                             const unsigned short* __restrict__ wph,
                                             const unsigned short* __restrict__ wpl,
                                             const float* __restrict__ dinv,
                                             unsigned short* __restrict__ hs1b) {
    const int lane = threadIdx.x & 63;
    const int gw = blockIdx.x * 4 + (threadIdx.x >> 6);
    const int node0 = gw * 16;
    if (node0 >= N_NODES) return;
    const int r16 = lane & 15, oct = lane >> 4;
    const int rowAc = min(node0 + r16, N_NODES - 1);   // clamp tail (stores guarded)

    const float* xr = x + (size_t)rowAc * D_IN + oct * 32;
    float rs = 0.f;
    #pragma unroll
    for (int q = 0; q < 8; ++q) {
        float4 v = ((const float4*)xr)[q];
        rs += (v.x + v.y) + (v.z + v.w);
    }
    rs += __shfl_xor(rs, 16, 64);
    rs += __shfl_xor(rs, 32, 64);
    const float ls = (1.0f / fmaxf(rs, 1.0f)) * dinv[rowAc];

    f32x4 acc[4] = {};   // one per 16-col ntile
    #pragma unroll
    for (int kt = 0; kt < 4; ++kt) {
        const float* ap = x + (size_t)rowAc * D_IN + kt * 32 + oct * 8;
        float4 a0 = ((const float4*)ap)[0];
        float4 a1 = ((const float4*)ap)[1];
        float f[8] = {a0.x, a0.y, a0.z, a0.w, a1.x, a1.y, a1.z, a1.w};
        bf16x8 ahi, alo;
        #pragma unroll
        for (int j = 0; j < 8; ++j) {
            float fs = f[j] * ls;
            unsigned int b = __float_as_uint(fs);
            ahi[j] = (short)(b >> 16);
            float fh = __uint_as_float(b & 0xffff0000u);
            alo[j] = (short)(__float_as_uint(fs - fh) >> 16);
        }
        #pragma unroll
        for (int nt = 0; nt < 4; ++nt) {
            int fo = ((kt * 4 + nt) * 64 + lane) * 8;
            bf16x8 bh = *(const bf16x8*)(wph + fo);
            bf16x8 bl = *(const bf16x8*)(wpl + fo);
            acc[nt] = __builtin_amdgcn_mfma_f32_16x16x32_bf16(ahi, bh, acc[nt], 0, 0, 0);
            acc[nt] = __builtin_amdgcn_mfma_f32_16x16x32_bf16(ahi, bl, acc[nt], 0, 0, 0);
            acc[nt] = __builtin_amdgcn_mfma_f32_16x16x32_bf16(alo, bh, acc[nt], 0, 0, 0);
        }
    }
    // C/D: col = lane&15, row = oct*4 + r   [m89 layout]
    #pragma unroll
    for (int nt = 0; nt < 4; ++nt) {
        #pragma unroll
        for (int r = 0; r < 4; ++r) {
            int node = node0 + oct * 4 + r;
            if (node < N_NODES)
                hs1b[(size_t)node * D_HID + nt * 16 + r16] = bf16r(acc[nt][r]);
        }
    }
}

// ----------------------------------------- fused gather1 + conv2 matmul -----
// R13 depth-1 schedule (proven best): raw idx early -> accumulate -> clamped
// row issue -> butterfly+mm2. Only the per-wave node batch shrank (G1_NT=4)
// to double wave-level parallelism.
__global__ __launch_bounds__(256) void k_g1m2(const int* __restrict__ rowptr,
                                              const int* __restrict__ csr_src,
                                              const unsigned short* __restrict__ hs1b,
                                              const float* __restrict__ dinv,
                                              const float* __restrict__ b1,
                                              const float* __restrict__ W2,
                                              unsigned short* __restrict__ hs2b) {
    const int lane = threadIdx.x & 63;
    const int g = lane >> 4;          // gather group 0..3
    const int q = lane & 15;          // channel-quad (h1 channels 4q..4q+3)
    const int c = lane & 31;          // output channel
    const int kh = lane >> 5;         // k-half for mm2

    float w2r[32];
    #pragma unroll
    for (int j = 0; j < 32; ++j) w2r[j] = W2[(kh * 32 + j) * D_OUT + c];  // coalesced
    const f32x4 bb = ((const f32x4*)b1)[q];

    const int node0 = (blockIdx.x * 4 + (threadIdx.x >> 6)) * G1_NT;
    if (node0 >= N_NODES) return;

    // ---- pipeline prologue (node0): raw indices then clamped row issue ----
    int begC = rowptr[node0];
    int endC = rowptr[node0 + 1];
    uint2 rowsC[PF1];
    {
        int raw[PF1];
        #pragma unroll
        for (int i = 0; i < PF1; ++i) raw[i] = csr_src[begC + g + 4 * i] & 0xFFFF;
        #pragma unroll
        for (int i = 0; i < PF1; ++i) {
            int idx = (begC + g + 4 * i < endC) ? raw[i] : 0;
            rowsC[i] = ((const uint2*)(hs1b + (size_t)idx * D_HID))[q];
        }
    }

    for (int t = 0; t < G1_NT; ++t) {
        const int v = node0 + t;
        if (v >= N_NODES) break;
        const bool haveNext = (t < G1_NT - 1) && (v + 1 < N_NODES);

        // (1) issue next node's INDEX loads unpredicated (fly during accumulate)
        const int begN = endC;
        int endN = endC;
        int rawN[PF1];
        if (haveNext) {
            endN = rowptr[v + 2];
            #pragma unroll
            for (int i = 0; i < PF1; ++i) rawN[i] = csr_src[begN + g + 4 * i] & 0xFFFF;
        }

        // (2) accumulate current node (waits rowsC — issued last iteration)
        f32x4 acc0 = {0,0,0,0}, acc1 = {0,0,0,0};
        if (g == 0) {   // self-loop
            uint2 w = ((const uint2*)(hs1b + (size_t)v * D_HID))[q];
            float2 t0 = bf2(w.x), t1 = bf2(w.y);
            acc0[0] += t0.x; acc0[1] += t0.y; acc0[2] += t1.x; acc0[3] += t1.y;
        }
        #pragma unroll
        for (int i = 0; i < PF1; ++i) {
            if (begC + g + 4 * i < endC) {
                float2 t0 = bf2(rowsC[i].x), t1 = bf2(rowsC[i].y);
                if (i & 1) { acc1[0]+=t0.x; acc1[1]+=t0.y; acc1[2]+=t1.x; acc1[3]+=t1.y; }
                else       { acc0[0]+=t0.x; acc0[1]+=t0.y; acc0[2]+=t1.x; acc0[3]+=t1.y; }
            }
        }
        for (int e = begC + g + 4 * PF1; e < endC; e += 4) {   // rare deg>32 tail
            int s = csr_src[e];
            uint2 w = ((const uint2*)(hs1b + (size_t)s * D_HID))[q];
            float2 t0 = bf2(w.x), t1 = bf2(w.y);
            acc0[0]+=t0.x; acc0[1]+=t0.y; acc0[2]+=t1.x; acc0[3]+=t1.y;
        }
        f32x4 acc = acc0 + acc1;

        // (3) issue next node's ROW loads with LATE clamp (endN now resident;
        //     the accumulate above covered its latency)
        uint2 rowsN[PF1];
        if (haveNext) {
            #pragma unroll
            for (int i = 0; i < PF1; ++i) {
                int idx = (begN + g + 4 * i < endN) ? rawN[i] : 0;
                rowsN[i] = ((const uint2*)(hs1b + (size_t)idx * D_HID))[q];
            }
        }

        // (4) butterfly across groups
        #pragma unroll
        for (int m = 16; m <= 32; m <<= 1) {
            f32x4 o;
            o[0] = __shfl_xor(acc[0], m, 64);
            o[1] = __shfl_xor(acc[1], m, 64);
            o[2] = __shfl_xor(acc[2], m, 64);
            o[3] = __shfl_xor(acc[3], m, 64);
            acc += o;
        }

        const float dv = dinv[v];
        f32x4 h;
        #pragma unroll
        for (int j = 0; j < 4; ++j) h[j] = fmaxf(dv * acc[j] + bb[j], 0.0f);

        // mm2: k = kh*32 + 4*qq + j  ->  quad Q = kh*8+qq held by lane Q
        float a = 0.0f;
        #pragma unroll
        for (int qq = 0; qq < 8; ++qq) {
            const int Q = kh * 8 + qq;
            a += __shfl(h[0], Q, 64) * w2r[4 * qq + 0];
            a += __shfl(h[1], Q, 64) * w2r[4 * qq + 1];
            a += __shfl(h[2], Q, 64) * w2r[4 * qq + 2];
            a += __shfl(h[3], Q, 64) * w2r[4 * qq + 3];
        }
        a += __shfl_xor(a, 32, 64);    // sum the two k-halves
        if (kh == 0) hs2b[(size_t)v * D_OUT + c] = bf16r(a * dv);

        // (5) shift pipeline state
        if (haveNext) {
            begC = begN; endC = endN;
            #pragma unroll
            for (int i = 0; i < PF1; ++i) rowsC[i] = rowsN[i];
        }
    }
}

// -------------------------------------------------------------- gather2 -----
// R13 depth-1 schedule + late clamp; G2_NT=4 for 2x waves. 8 groups x 8
// lanes; PF2=4 covers deg<=32. Fused epilogue: p = relu(dinv*agg + b2).
__global__ __launch_bounds__(256) void k_gather2(const int* __restrict__ rowptr,
                                                 const int* __restrict__ csr_src,
                                                 const unsigned short* __restrict__ hs2b,
                                                 const float* __restrict__ dinv,
                                                 const float* __restrict__ b2,
                                                 float* __restrict__ p) {
    const int lane = threadIdx.x & 63;
    const int g = lane >> 3;          // group 0..7
    const int q = lane & 7;           // channel-quad index

    const int node0 = (blockIdx.x * 4 + (threadIdx.x >> 6)) * G2_NT;
    if (node0 >= N_NODES) return;
    const f32x4 bb = ((const f32x4*)b2)[q];

    int begC = rowptr[node0];
    int endC = rowptr[node0 + 1];
    uint2 rowsC[PF2];
    {
        int raw[PF2];
        #pragma unroll
        for (int i = 0; i < PF2; ++i) raw[i] = csr_src[begC + g + 8 * i] & 0xFFFF;
        #pragma unroll
        for (int i = 0; i < PF2; ++i) {
            int idx = (begC + g + 8 * i < endC) ? raw[i] : 0;
            rowsC[i] = ((const uint2*)(hs2b + (size_t)idx * D_OUT))[q];
        }
    }

    for (int t = 0; t < G2_NT; ++t) {
        const int v = node0 + t;
        if (v >= N_NODES) break;
        const bool haveNext = (t < G2_NT - 1) && (v + 1 < N_NODES);

        const int begN = endC;
        int endN = endC;
        int rawN[PF2];
        if (haveNext) {
            endN = rowptr[v + 2];
            #pragma unroll
            for (int i = 0; i < PF2; ++i) rawN[i] = csr_src[begN + g + 8 * i] & 0xFFFF;
        }

        f32x4 acc = {0,0,0,0};
        if (g == 0) {   // self-loop
            uint2 w = ((const uint2*)(hs2b + (size_t)v * D_OUT))[q];
            float2 t0 = bf2(w.x), t1 = bf2(w.y);
            acc[0] += t0.x; acc[1] += t0.y; acc[2] += t1.x; acc[3] += t1.y;
        }
        #pragma unroll
        for (int i = 0; i < PF2; ++i) {
            if (begC + g + 8 * i < endC) {
                float2 t0 = bf2(rowsC[i].x), t1 = bf2(rowsC[i].y);
                acc[0] += t0.x; acc[1] += t0.y; acc[2] += t1.x; acc[3] += t1.y;
            }
        }
        for (int e = begC + g + 8 * PF2; e < endC; e += 8) {   // rare deg>32 tail
            int s = csr_src[e];
            uint2 w = ((const uint2*)(hs2b + (size_t)s * D_OUT))[q];
            float2 t0 = bf2(w.x), t1 = bf2(w.y);
            acc[0] += t0.x; acc[1] += t0.y; acc[2] += t1.x; acc[3] += t1.y;
        }

        uint2 rowsN[PF2];
        if (haveNext) {
            #pragma unroll
            for (int i = 0; i < PF2; ++i) {
                int idx = (begN + g + 8 * i < endN) ? rawN[i] : 0;
                rowsN[i] = ((const uint2*)(hs2b + (size_t)idx * D_OUT))[q];
            }
        }

        #pragma unroll
        for (int m = 8; m <= 32; m <<= 1) {
            f32x4 o;
            o[0] = __shfl_xor(acc[0], m, 64);
            o[1] = __shfl_xor(acc[1], m, 64);
            o[2] = __shfl_xor(acc[2], m, 64);
            o[3] = __shfl_xor(acc[3], m, 64);
            acc += o;
        }

        if (g == 0) {
            const float dv = dinv[v];
            f32x4 r;
            #pragma unroll
            for (int j = 0; j < 4; ++j) r[j] = fmaxf(dv * acc[j] + bb[j], 0.0f);
            ((f32x4*)(p + (size_t)v * D_OUT))[q] = r;
        }

        if (haveNext) {
            begC = begN; endC = endN;
            #pragma unroll
            for (int i = 0; i < PF2; ++i) rowsC[i] = rowsN[i];
        }
    }
}

// ----------------------------------------------------------- mean pool ------
__global__ __launch_bounds__(256) void k_pool(const float* __restrict__ p,
                                              const int* __restrict__ batch,
                                              float* __restrict__ psum) {
    const int c = threadIdx.x & 31;
    const int slot = threadIdx.x >> 5;
    const int base = blockIdx.x * POOL_TILE;

    float acc = 0.0f;
    int curg = -1;
    for (int j = slot; j < POOL_TILE; j += 8) {
        int node = base + j;
        if (node >= N_NODES) break;
        float hv = p[(size_t)node * D_OUT + c];
        int g = batch[node];
        if (g != curg) {
            if (curg >= 0) atomicAdd(&psum[curg * D_OUT + c], acc);
            curg = g;
            acc = 0.0f;
        }
        acc += hv;
    }
    if (curg >= 0) atomicAdd(&psum[curg * D_OUT + c], acc);
}

__global__ __launch_bounds__(256) void k_final(const float* __restrict__ psum,
                                               const int* __restrict__ batch,
                                               float* __restrict__ out) {
    int i = blockIdx.x * 256 + threadIdx.x;
    if (i < N_GRAPHS * D_OUT) {
        int g = i >> 5;   // D_OUT == 32
        int lo = 0, hi = N_NODES;
        while (lo < hi) { int m = (lo + hi) >> 1; if (batch[m] < g) lo = m + 1; else hi = m; }
        int lb = lo;
        lo = 0; hi = N_NODES;
        while (lo < hi) { int m = (lo + hi) >> 1; if (batch[m] <= g) lo = m + 1; else hi = m; }
        float cnt = (float)(lo - lb);
        out[i] = psum[i] / fmaxf(cnt, 1.0f);
    }
}

// ---------------------------------------------------------------------------
extern "C" void kernel_launch(void* const* d_in, const int* in_sizes, int n_in,
                              void* d_out, int out_size, void* d_ws, size_t ws_size,
                              hipStream_t stream) {
    const float* x     = (const float*)d_in[0];
    const int*   edge  = (const int*)d_in[1];   // [2, E]
    const int*   batch = (const int*)d_in[2];   // [N] sorted
    const float* W1    = (const float*)d_in[3];
    const float* b1    = (const float*)d_in[4];
    const float* W2    = (const float*)d_in[5];
    const float* b2    = (const float*)d_in[6];
    float* out = (float*)d_out;

    const int* src = edge;
    const int* dst = edge + N_EDGES;

    float* ws   = (float*)d_ws;
    float* dinv = ws;                                        // N floats
    unsigned short* hs1b = (unsigned short*)(dinv + N_NODES);     // N*64 bf16
    unsigned short* hs2b = hs1b + (size_t)N_NODES * D_HID;        // N*32 bf16
    float* p    = (float*)(hs2b + (size_t)N_NODES * D_OUT);       // N*32 f32
    float* psum = p + (size_t)N_NODES * D_OUT;                    // G*32
    int* bin_cursor = (int*)(psum + N_GRAPHS * D_OUT);            // NPART
    int* rowptr  = bin_cursor + NPART;                            // N+1
    int* csr_src = rowptr + N_NODES + 1;                          // E
    unsigned int* binbuf = (unsigned int*)(csr_src + N_EDGES);    // NPART*BSTRIDE
    unsigned short* wph = (unsigned short*)(binbuf + (size_t)NPART * BSTRIDE);  // 8192
    unsigned short* wpl = wph + D_IN * D_HID;                                   // 8192

    k_init   <<<1, 256, 0, stream>>>(W1, wph, wpl, psum, bin_cursor);
    k_binA   <<<(N_EDGES + EPB - 1) / EPB, 256, 0, stream>>>(src, dst, bin_cursor, binbuf);
    k_csr    <<<NPART, 256, 0, stream>>>(bin_cursor, binbuf, rowptr, dinv, csr_src);
    k_mm1    <<<(N_NODES + 63) / 64, 256, 0, stream>>>(x, wph, wpl, dinv, hs1b);
    k_g1m2   <<<(N_NODES + 4 * G1_NT - 1) / (4 * G1_NT), 256, 0, stream>>>(rowptr, csr_src, hs1b, dinv, b1, W2, hs2b);
    k_gather2<<<(N_NODES + 4 * G2_NT - 1) / (4 * G2_NT), 256, 0, stream>>>(rowptr, csr_src, hs2b, dinv, b2, p);
    k_pool   <<<(N_NODES + POOL_TILE - 1) / POOL_TILE, 256, 0, stream>>>(p, batch, psum);
    k_final  <<<(N_GRAPHS * D_OUT + 255) / 256, 256, 0, stream>>>(psum, batch, out);
}